// Round 2
// baseline (482.383 us; speedup 1.0000x reference)
//
#include <hip/hip_runtime.h>
#include <hip/hip_bf16.h>

#define NB 32
#define NL 2048
#define ND 1024
#define ND2 512

typedef unsigned short ushort_t;

__device__ __forceinline__ float bf2f(unsigned int u16) {
    return __uint_as_float(u16 << 16);
}
__device__ __forceinline__ void cvt8(uint4 v, float* f) {
    f[0] = bf2f(v.x & 0xffffu); f[1] = bf2f(v.x >> 16);
    f[2] = bf2f(v.y & 0xffffu); f[3] = bf2f(v.y >> 16);
    f[4] = bf2f(v.z & 0xffffu); f[5] = bf2f(v.z >> 16);
    f[6] = bf2f(v.w & 0xffffu); f[7] = bf2f(v.w >> 16);
}
// Load 8 consecutive elements (element index `idx`, multiple of 8) as f32.
__device__ __forceinline__ void load8(const void* p, size_t idx, int isf32, float* f) {
    if (isf32) {
        const float4* fp = (const float4*)((const float*)p + idx);
        float4 a = fp[0], b = fp[1];
        f[0]=a.x; f[1]=a.y; f[2]=a.z; f[3]=a.w;
        f[4]=b.x; f[5]=b.y; f[6]=b.z; f[7]=b.w;
    } else {
        uint4 v = *(const uint4*)((const ushort_t*)p + idx);
        cvt8(v, f);
    }
}
__device__ __forceinline__ float load1(const void* p, int idx, int isf32) {
    return isf32 ? ((const float*)p)[idx] : bf2f(((const ushort_t*)p)[idx]);
}
__device__ __forceinline__ void store1(void* p, size_t idx, float v, int isf32) {
    if (isf32) ((float*)p)[idx] = v;
    else ((__hip_bfloat16*)p)[idx] = __float2bfloat16(v);
}
__device__ __forceinline__ float waveReduceSum(float v) {
    for (int off = 32; off > 0; off >>= 1) v += __shfl_down(v, off, 64);
    return v;
}

// Detect input dtype: bf16 normal data never has exponent==0xFF; f32 data
// reinterpreted as u16 halves hits it ~1/256 per low half. flag=1 => f32.
__global__ void k_detect(const ushort_t* __restrict__ ctx, int* __restrict__ flag) {
    __shared__ int found;
    if (threadIdx.x == 0) found = 0;
    __syncthreads();
    int cnt = 0;
    for (int i = threadIdx.x; i < 16384; i += 256) {
        unsigned e = (ctx[i] >> 7) & 0xFFu;
        if (e == 0xFFu) cnt++;
    }
    if (cnt) atomicOr(&found, 1);
    __syncthreads();
    if (threadIdx.x == 0) *flag = found;
}

// q[b,e] = sum_d query[b,d] * W_in[e,d]; one wave per (b,e)
__global__ __launch_bounds__(256) void k_qproj(const void* __restrict__ query,
                                               const void* __restrict__ W_in,
                                               float* __restrict__ q,
                                               const int* __restrict__ flag) {
    int isf32 = *flag;
    int wave = blockIdx.x * 4 + (threadIdx.x >> 6);
    int lane = threadIdx.x & 63;
    int b = wave >> 10;
    int e = wave & 1023;
    size_t qb = (size_t)b * ND + lane * 16;
    size_t wb = (size_t)e * ND + lane * 16;
    float qa[8], qc[8], wa[8], wc[8];
    load8(query, qb, isf32, qa); load8(query, qb + 8, isf32, qc);
    load8(W_in, wb, isf32, wa);  load8(W_in, wb + 8, isf32, wc);
    float s = 0.f;
    for (int i = 0; i < 8; i++) s += qa[i] * wa[i] + qc[i] * wc[i];
    s = waveReduceSum(s);
    if (lane == 0) q[b * ND + e] = s;
}

// scores[b,l] = q[b,:] . ctx[b,l,:]; one wave per (b, 4 l's)
__global__ __launch_bounds__(256) void k_scores(const float* __restrict__ q,
                                                const void* __restrict__ ctx,
                                                float* __restrict__ scores,
                                                const int* __restrict__ flag) {
    int isf32 = *flag;
    int wave = blockIdx.x * 4 + (threadIdx.x >> 6);
    int lane = threadIdx.x & 63;
    int b = wave >> 9;
    int lg = wave & 511;
    int l0 = lg * 4;
    const float4* qp = (const float4*)(q + b * ND) + lane * 4;
    float4 q0 = qp[0], q1 = qp[1], q2 = qp[2], q3 = qp[3];
    for (int j = 0; j < 4; j++) {
        int l = l0 + j;
        size_t base = ((size_t)b * NL + l) * ND + lane * 16;
        float ca[8], cb[8];
        load8(ctx, base, isf32, ca); load8(ctx, base + 8, isf32, cb);
        float s = q0.x*ca[0]+q0.y*ca[1]+q0.z*ca[2]+q0.w*ca[3]
                + q1.x*ca[4]+q1.y*ca[5]+q1.z*ca[6]+q1.w*ca[7]
                + q2.x*cb[0]+q2.y*cb[1]+q2.z*cb[2]+q2.w*cb[3]
                + q3.x*cb[4]+q3.y*cb[5]+q3.z*cb[6]+q3.w*cb[7];
        s = waveReduceSum(s);
        if (lane == 0) scores[b * NL + l] = s;
    }
}

// softmax per b; attn (f32) in-place over scores, c2 = ae*attn*exp(-ab*dt),
// attn also to d_out tail (output dtype per flag).
__global__ __launch_bounds__(256) void k_softmax(float* __restrict__ scores,
                                                 const void* __restrict__ ae,
                                                 const void* __restrict__ ab,
                                                 float* __restrict__ c2,
                                                 void* __restrict__ d_out,
                                                 const int* __restrict__ flag) {
    int isf32 = *flag;
    int b = blockIdx.x;
    int tid = threadIdx.x;
    __shared__ float red[256];
    float s[8];
    for (int k = 0; k < 8; k++) s[k] = scores[b * NL + tid + k * 256];
    float m = s[0];
    for (int k = 1; k < 8; k++) m = fmaxf(m, s[k]);
    red[tid] = m; __syncthreads();
    for (int step = 128; step > 0; step >>= 1) {
        if (tid < step) red[tid] = fmaxf(red[tid], red[tid + step]);
        __syncthreads();
    }
    m = red[0]; __syncthreads();
    float e[8], loc = 0.f;
    for (int k = 0; k < 8; k++) { e[k] = expf(s[k] - m); loc += e[k]; }
    red[tid] = loc; __syncthreads();
    for (int step = 128; step > 0; step >>= 1) {
        if (tid < step) red[tid] += red[tid + step];
        __syncthreads();
    }
    float inv = 1.f / red[0];
    float aev = load1(ae, b, isf32), abv = load1(ab, b, isf32);
    for (int k = 0; k < 8; k++) {
        int l = tid + k * 256;
        float a = e[k] * inv;
        scores[b * NL + l] = a;
        c2[b * NL + l] = aev * a * expf(-abv * (float)(NL - 1 - l));
        store1(d_out, (size_t)NB * ND2 + b * NL + l, a, isf32);
    }
}

// partials[b,chunk,d] = sum over 128 l's of attn_l*ctx + c2_l*relu(ctx)
#define LCHUNK 128
__global__ __launch_bounds__(256) void k_mix(const void* __restrict__ ctx,
                                             const float* __restrict__ attn,
                                             const float* __restrict__ c2,
                                             float* __restrict__ partials,
                                             const int* __restrict__ flag) {
    int isf32 = *flag;
    int b = blockIdx.x >> 4;
    int chunk = blockIdx.x & 15;
    int l0 = chunk * LCHUNK;
    int tid = threadIdx.x;
    __shared__ float sc1[LCHUNK], sc2[LCHUNK];
    __shared__ float comb[128 * 8];
    if (tid < LCHUNK) sc1[tid] = attn[b * NL + l0 + tid];
    else sc2[tid - LCHUNK] = c2[b * NL + l0 + tid - LCHUNK];
    __syncthreads();
    int half = tid >> 7;
    int dgrp = tid & 127;
    int d0 = dgrp * 8;
    float acc[8];
    for (int j = 0; j < 8; j++) acc[j] = 0.f;
    for (int l = half; l < LCHUNK; l += 2) {
        float f[8];
        load8(ctx, ((size_t)b * NL + l0 + l) * ND + d0, isf32, f);
        float a = sc1[l], k2 = sc2[l];
        for (int j = 0; j < 8; j++) acc[j] += a * f[j] + k2 * fmaxf(f[j], 0.f);
    }
    if (half == 1) {
        for (int j = 0; j < 8; j++) comb[dgrp * 8 + j] = acc[j];
    }
    __syncthreads();
    if (half == 0) {
        float* outp = partials + ((size_t)(b * 16 + chunk)) * ND + d0;
        for (int j = 0; j < 8; j++) outp[j] = acc[j] + comb[dgrp * 8 + j];
    }
}

// mixed[b,d] = sum over 16 chunks
__global__ __launch_bounds__(256) void k_reduce(const float* __restrict__ partials,
                                               float* __restrict__ mixed) {
    int idx = blockIdx.x * 256 + threadIdx.x; // 32768
    int b = idx >> 10, d = idx & 1023;
    float s = 0.f;
    for (int c = 0; c < 16; c++) s += partials[((size_t)(b * 16 + c)) * ND + d];
    mixed[idx] = s;
}

// out[b,e] = tanh( [mixed,q][b,:] . W_out[e,:] ); one wave per (b,e)
__global__ __launch_bounds__(256) void k_out(const float* __restrict__ mixed,
                                             const float* __restrict__ q,
                                             const void* __restrict__ W_out,
                                             void* __restrict__ d_out,
                                             const int* __restrict__ flag) {
    int isf32 = *flag;
    int wave = blockIdx.x * 4 + (threadIdx.x >> 6);
    int lane = threadIdx.x & 63;
    int b = wave >> 9;
    int e = wave & 511;
    int c0 = lane * 32;
    const float* src = (lane < 32) ? (mixed + b * ND + c0) : (q + b * ND + c0 - ND);
    float s = 0.f;
    for (int t = 0; t < 4; t++) {
        float w[8];
        load8(W_out, (size_t)e * 2 * ND + c0 + t * 8, isf32, w);
        const float4* sp = (const float4*)(src + t * 8);
        float4 s0 = sp[0], s1 = sp[1];
        s += w[0]*s0.x + w[1]*s0.y + w[2]*s0.z + w[3]*s0.w
           + w[4]*s1.x + w[5]*s1.y + w[6]*s1.z + w[7]*s1.w;
    }
    s = waveReduceSum(s);
    if (lane == 0) store1(d_out, (size_t)b * ND2 + e, tanhf(s), isf32);
}

extern "C" void kernel_launch(void* const* d_in, const int* in_sizes, int n_in,
                              void* d_out, int out_size, void* d_ws, size_t ws_size,
                              hipStream_t stream) {
    const void* query = d_in[0];
    const void* ctx   = d_in[1];
    const void* W_in  = d_in[2];
    const void* W_out = d_in[3];
    const void* ae    = d_in[4];
    const void* ab    = d_in[5];

    float* ws       = (float*)d_ws;
    float* q        = ws;            // 32768
    float* scores   = ws + 32768;    // 65536 (becomes attn f32)
    float* c2       = ws + 98304;    // 65536
    float* partials = ws + 163840;   // 16*32768 = 524288
    float* mixed    = ws + 688128;   // 32768
    int*   flag     = (int*)(ws + 720896);

    k_detect <<<   1, 256, 0, stream>>>((const ushort_t*)ctx, flag);
    k_qproj  <<<8192, 256, 0, stream>>>(query, W_in, q, flag);
    k_scores <<<4096, 256, 0, stream>>>(q, ctx, scores, flag);
    k_softmax<<<  32, 256, 0, stream>>>(scores, ae, ab, c2, d_out, flag);
    k_mix    <<< 512, 256, 0, stream>>>(ctx, scores, c2, partials, flag);
    k_reduce <<< 128, 256, 0, stream>>>(partials, mixed);
    k_out    <<<4096, 256, 0, stream>>>(mixed, q, W_out, d_out, flag);
}

// Round 3
// 428.957 us; speedup vs baseline: 1.1245x; 1.1245x over previous
//
#include <hip/hip_runtime.h>
#include <hip/hip_bf16.h>
#include <math.h>

// Shapes (fixed by the problem): B=32, O=1, L=2048, D=1024, D2=512.
// All inputs/outputs are float32 (verified round 2: bf16 interpretation NaN'd,
// f32 path passed with absmax 2e-3).
#define NB 32
#define NL 2048
#define ND 1024
#define ND2 512
#define CH 32           // l-chunks per batch for k_flash
#define ROWS (NL / CH)  // 64 rows per block
#define RPW (ROWS / 4)  // 16 rows per wave

__device__ __forceinline__ float waveReduceSumAll(float v) {
    // butterfly: every lane ends with the full 64-lane sum
    for (int off = 32; off > 0; off >>= 1) v += __shfl_xor(v, off, 64);
    return v;
}
__device__ __forceinline__ float waveReduceSum(float v) {
    for (int off = 32; off > 0; off >>= 1) v += __shfl_down(v, off, 64);
    return v;
}

// q[b,e] = sum_d query[b,d] * W_in[e,d]; one wave per (b,e). 8192 blocks.
__global__ __launch_bounds__(256) void k_qproj(const float* __restrict__ query,
                                               const float* __restrict__ W_in,
                                               float* __restrict__ q) {
    int wave = blockIdx.x * 4 + (threadIdx.x >> 6);
    int lane = threadIdx.x & 63;
    int b = wave >> 10;
    int e = wave & 1023;
    const float4* qr = (const float4*)(query + (size_t)b * ND) + lane * 4;
    const float4* wr = (const float4*)(W_in + (size_t)e * ND) + lane * 4;
    float s = 0.f;
#pragma unroll
    for (int t = 0; t < 4; t++) {
        float4 a = qr[t], w = wr[t];
        s += a.x * w.x + a.y * w.y + a.z * w.z + a.w * w.w;
    }
    s = waveReduceSum(s);
    if (lane == 0) q[b * ND + e] = s;
}

// Single pass over context: per (b, chunk) block, per-wave online softmax +
// weighted accumulation. Emits raw scores + per-block partials (m, Z, acc[ND]).
__global__ __launch_bounds__(256) void k_flash(const float* __restrict__ q,
                                               const float* __restrict__ ctx,
                                               const float* __restrict__ ae,
                                               const float* __restrict__ ab,
                                               float* __restrict__ scores,
                                               float* __restrict__ pm,
                                               float* __restrict__ pZ,
                                               float* __restrict__ pacc) {
    int b = blockIdx.x >> 5;       // CH == 32
    int chunk = blockIdx.x & 31;
    int wave = threadIdx.x >> 6;
    int lane = threadIdx.x & 63;

    // q fragment: 16 consecutive floats per lane
    const float4* qp = (const float4*)(q + (size_t)b * ND) + lane * 4;
    float4 q0 = qp[0], q1 = qp[1], q2 = qp[2], q3 = qp[3];
    float aev = ae[b], abv = ab[b];

    float m = -INFINITY, Z = 0.f;
    float acc[16];
#pragma unroll
    for (int j = 0; j < 16; j++) acc[j] = 0.f;

    int l0 = chunk * ROWS + wave * RPW;
    for (int i = 0; i < RPW; i++) {
        int l = l0 + i;
        const float4* cp = (const float4*)(ctx + ((size_t)b * NL + l) * ND) + lane * 4;
        float4 c0 = cp[0], c1 = cp[1], c2 = cp[2], c3 = cp[3];
        float s = c0.x*q0.x + c0.y*q0.y + c0.z*q0.z + c0.w*q0.w
                + c1.x*q1.x + c1.y*q1.y + c1.z*q1.z + c1.w*q1.w
                + c2.x*q2.x + c2.y*q2.y + c2.z*q2.z + c2.w*q2.w
                + c3.x*q3.x + c3.y*q3.y + c3.z*q3.z + c3.w*q3.w;
        s = waveReduceSumAll(s);
        if (lane == 0) scores[b * NL + l] = s;

        float bt = __expf(-abv * (float)(NL - 1 - l));
        if (s > m) {                      // wave-uniform branch
            float sc = __expf(m - s);     // 0 on first row (m = -inf)
            m = s;
            Z *= sc;
#pragma unroll
            for (int j = 0; j < 16; j++) acc[j] *= sc;
        }
        float p = __expf(s - m);
        float k2 = p * aev * bt;
        Z += p;
        float c[16] = {c0.x,c0.y,c0.z,c0.w, c1.x,c1.y,c1.z,c1.w,
                       c2.x,c2.y,c2.z,c2.w, c3.x,c3.y,c3.z,c3.w};
#pragma unroll
        for (int j = 0; j < 16; j++)
            acc[j] += p * c[j] + k2 * fmaxf(c[j], 0.f);
    }

    // merge the 4 waves of this block
    __shared__ float sacc[4 * ND];   // 16 KB
    __shared__ float sm[4], sZ[4];
#pragma unroll
    for (int j = 0; j < 16; j++) sacc[wave * ND + lane * 16 + j] = acc[j];
    if (lane == 0) { sm[wave] = m; sZ[wave] = Z; }
    __syncthreads();

    int tid = threadIdx.x;
    float m0 = sm[0], m1 = sm[1], m2 = sm[2], m3 = sm[3];
    float mb = fmaxf(fmaxf(m0, m1), fmaxf(m2, m3));
    float e0 = __expf(m0 - mb), e1 = __expf(m1 - mb),
          e2 = __expf(m2 - mb), e3 = __expf(m3 - mb);
    int d = tid * 4;
    float4 v;
    v.x = e0*sacc[0*ND+d+0] + e1*sacc[1*ND+d+0] + e2*sacc[2*ND+d+0] + e3*sacc[3*ND+d+0];
    v.y = e0*sacc[0*ND+d+1] + e1*sacc[1*ND+d+1] + e2*sacc[2*ND+d+1] + e3*sacc[3*ND+d+1];
    v.z = e0*sacc[0*ND+d+2] + e1*sacc[1*ND+d+2] + e2*sacc[2*ND+d+2] + e3*sacc[3*ND+d+2];
    v.w = e0*sacc[0*ND+d+3] + e1*sacc[1*ND+d+3] + e2*sacc[2*ND+d+3] + e3*sacc[3*ND+d+3];
    *(float4*)(pacc + ((size_t)(b * CH + chunk)) * ND + d) = v;
    if (tid == 0) {
        pm[b * CH + chunk] = mb;
        pZ[b * CH + chunk] = e0*sZ[0] + e1*sZ[1] + e2*sZ[2] + e3*sZ[3];
    }
}

// Per-b merge of CH partials -> mixed[b,:], plus exact attn output.
__global__ __launch_bounds__(256) void k_merge(const float* __restrict__ pm,
                                               const float* __restrict__ pZ,
                                               const float* __restrict__ pacc,
                                               const float* __restrict__ scores,
                                               float* __restrict__ mixed,
                                               float* __restrict__ attn_out) {
    int b = blockIdx.x;
    int tid = threadIdx.x;
    __shared__ float ew[CH];
    __shared__ float smg, sinvZ;
    if (tid == 0) {
        float mg = -INFINITY;
        for (int i = 0; i < CH; i++) mg = fmaxf(mg, pm[b * CH + i]);
        float Zg = 0.f;
        for (int i = 0; i < CH; i++) Zg += __expf(pm[b * CH + i] - mg) * pZ[b * CH + i];
        smg = mg; sinvZ = 1.f / Zg;
    }
    __syncthreads();
    float mg = smg, invZ = sinvZ;
    if (tid < CH) ew[tid] = __expf(pm[b * CH + tid] - mg);
    __syncthreads();

    int d = tid * 4;
    float4 accv = {0.f, 0.f, 0.f, 0.f};
    for (int i = 0; i < CH; i++) {
        float4 pv = *(const float4*)(pacc + ((size_t)(b * CH + i)) * ND + d);
        float e = ew[i];
        accv.x += e * pv.x; accv.y += e * pv.y;
        accv.z += e * pv.z; accv.w += e * pv.w;
    }
    accv.x *= invZ; accv.y *= invZ; accv.z *= invZ; accv.w *= invZ;
    *(float4*)(mixed + (size_t)b * ND + d) = accv;

    for (int l = tid; l < NL; l += 256)
        attn_out[b * NL + l] = __expf(scores[b * NL + l] - mg) * invZ;
}

// out[b,e] = tanh( [mixed,q][b,:] . W_out[e,:] ); one wave per (b,e). 4096 blocks.
__global__ __launch_bounds__(256) void k_out(const float* __restrict__ mixed,
                                             const float* __restrict__ q,
                                             const float* __restrict__ W_out,
                                             float* __restrict__ out) {
    int wave = blockIdx.x * 4 + (threadIdx.x >> 6);
    int lane = threadIdx.x & 63;
    int b = wave >> 9;
    int e = wave & 511;
    int c0 = lane * 32;   // 32 consecutive floats of the 2048-dim combined vec
    const float* src = (lane < 32) ? (mixed + (size_t)b * ND + c0)
                                   : (q + (size_t)b * ND + c0 - ND);
    const float4* wr = (const float4*)(W_out + (size_t)e * 2 * ND + c0);
    const float4* sp = (const float4*)src;
    float s = 0.f;
#pragma unroll
    for (int t = 0; t < 8; t++) {
        float4 w = wr[t], x = sp[t];
        s += w.x * x.x + w.y * x.y + w.z * x.z + w.w * x.w;
    }
    s = waveReduceSum(s);
    if (lane == 0) out[b * ND2 + e] = tanhf(s);
}

extern "C" void kernel_launch(void* const* d_in, const int* in_sizes, int n_in,
                              void* d_out, int out_size, void* d_ws, size_t ws_size,
                              hipStream_t stream) {
    const float* query = (const float*)d_in[0];
    const float* ctx   = (const float*)d_in[1];
    const float* W_in  = (const float*)d_in[2];
    const float* W_out = (const float*)d_in[3];
    const float* ae    = (const float*)d_in[4];
    const float* ab    = (const float*)d_in[5];
    float* out = (float*)d_out;                    // [NB, ND2]
    float* attn_out = out + (size_t)NB * ND2;      // [NB, NL]

    float* ws     = (float*)d_ws;
    float* q      = ws;                        // 32768
    float* scores = ws + 32768;                // 65536
    float* pm     = ws + 98304;                // 1024
    float* pZ     = ws + 99328;                // 1024
    float* pacc   = ws + 100352;               // NB*CH*ND = 1048576
    float* mixed  = ws + 1148928;              // 32768

    k_qproj<<<8192, 256, 0, stream>>>(query, W_in, q);
    k_flash<<<NB * CH, 256, 0, stream>>>(q, ctx, ae, ab, scores, pm, pZ, pacc);
    k_merge<<<NB, 256, 0, stream>>>(pm, pZ, pacc, scores, mixed, attn_out);
    k_out<<<4096, 256, 0, stream>>>(mixed, q, W_out, out);
}